// Round 16
// baseline (139.779 us; speedup 1.0000x reference)
//
#include <hip/hip_runtime.h>
#include <hip/hip_bf16.h>

#define HW 4096
#define CIN 192
#define CMID 96

typedef __attribute__((ext_vector_type(8))) short bf16x8;
typedef __attribute__((ext_vector_type(4))) float f32x4;
typedef __attribute__((ext_vector_type(16))) float f32x16;
typedef __attribute__((ext_vector_type(4))) unsigned int u32x4;

static __device__ __forceinline__ unsigned short f2bf(float f) {
    union { float f; unsigned int u; } v;
    v.f = f;
    unsigned int r = v.u + 0x7fffu + ((v.u >> 16) & 1u);
    return (unsigned short)(r >> 16);
}

// (1/64) * log2(e), folded into Q at projection time
#define SCQ (0.015625f * 1.44269504089f)

// ---------------------------------------------------------------------------
// Kernel 0: convert weights to bf16.
// ---------------------------------------------------------------------------
__global__ __launch_bounds__(256) void convw_kernel(
    const float* __restrict__ wq, const float* __restrict__ wk,
    const float* __restrict__ wv, const float* __restrict__ wz,
    unsigned short* __restrict__ wqkvb, unsigned short* __restrict__ wzb)
{
    int idx = blockIdx.x * 256 + threadIdx.x;
    if (idx < 3 * CMID * CIN) {
        int m = idx / (CMID * CIN), r = idx % (CMID * CIN);
        const float* w = (m == 0) ? wq : ((m == 1) ? wk : wv);
        wqkvb[idx] = f2bf(w[r]);
    } else if (idx < 3 * CMID * CIN + CIN * CMID) {
        int r = idx - 3 * CMID * CIN;
        wzb[r] = f2bf(wz[r]);
    }
}

// ---------------------------------------------------------------------------
// Kernel 1: Q/K/V projections (bf16 MFMA), fragment-major outputs.
// Unchanged from R13.
// ---------------------------------------------------------------------------
__global__ __launch_bounds__(512) void qkv_kernel(
    const float* __restrict__ x, const float* __restrict__ pe,
    const unsigned short* __restrict__ wqkvb,
    const float* __restrict__ bq, const float* __restrict__ bk,
    const float* __restrict__ bv,
    unsigned short* __restrict__ QF, unsigned short* __restrict__ KF,
    unsigned short* __restrict__ VF)
{
    const int n = blockIdx.y, bx = blockIdx.x, i0 = bx * 64, t = threadIdx.x;
    __shared__ unsigned short xt[64 * 200];

    #pragma unroll
    for (int it = 0; it < 6; ++it) {
        int q = t + it * 512;
        int c = q >> 4, il4 = (q & 15) << 2;
        f32x4 xv = *(const f32x4*)(x + ((size_t)n * CIN + c) * HW + i0 + il4);
        f32x4 pv = *(const f32x4*)(pe + c * 14400 + bx * 120 + il4);
        float a0 = xv[0] + pv[0], a1 = xv[1] + pv[1];
        float a2 = xv[2] + pv[2], a3 = xv[3] + pv[3];
        unsigned w01, w23;
        asm("v_cvt_pk_bf16_f32 %0, %1, %2" : "=v"(w01) : "v"(a0), "v"(a1));
        asm("v_cvt_pk_bf16_f32 %0, %1, %2" : "=v"(w23) : "v"(a2), "v"(a3));
        xt[(il4 + 0) * 200 + c] = (unsigned short)w01;
        xt[(il4 + 1) * 200 + c] = (unsigned short)(w01 >> 16);
        xt[(il4 + 2) * 200 + c] = (unsigned short)w23;
        xt[(il4 + 3) * 200 + c] = (unsigned short)(w23 >> 16);
    }
    __syncthreads();

    const int w = t >> 6, lane = t & 63, l15 = lane & 15, lg = lane >> 4;
    const int wg = w >> 2;
    const int p0 = (w & 3) * 16;

    bf16x8 af[6];
    #pragma unroll
    for (int f = 0; f < 6; ++f)
        af[f] = *(const bf16x8*)(xt + (p0 + l15) * 200 + f * 32 + lg * 8);

    #pragma unroll
    for (int cc = 0; cc < 9; ++cc) {
        const int ct = wg * 9 + cc;
        const int m = ct / 6, c6 = ct % 6;
        f32x4 acc = (f32x4){0.f, 0.f, 0.f, 0.f};
        const unsigned short* wrow = wqkvb + (ct * 16 + l15) * CIN + lg * 8;
        #pragma unroll
        for (int f = 0; f < 6; ++f) {
            bf16x8 wf = *(const bf16x8*)(wrow + f * 32);
            if (m < 2)
                acc = __builtin_amdgcn_mfma_f32_16x16x32_bf16(wf, af[f], acc, 0, 0, 0);
            else
                acc = __builtin_amdgcn_mfma_f32_16x16x32_bf16(af[f], wf, acc, 0, 0, 0);
        }
        if (m < 2) {
            f32x4 bv4 = *(const f32x4*)(((m == 0) ? bq : bk) + c6 * 16 + lg * 4);
            ushort4 pk4;
            if (m == 0) {
                pk4.x = f2bf((acc[0] + bv4[0]) * SCQ);
                pk4.y = f2bf((acc[1] + bv4[1]) * SCQ);
                pk4.z = f2bf((acc[2] + bv4[2]) * SCQ);
                pk4.w = f2bf((acc[3] + bv4[3]) * SCQ);
            } else {
                pk4.x = f2bf(acc[0] + bv4[0]);
                pk4.y = f2bf(acc[1] + bv4[1]);
                pk4.z = f2bf(acc[2] + bv4[2]);
                pk4.w = f2bf(acc[3] + bv4[3]);
            }
            const int p = i0 + p0 + l15;
            unsigned short* dst = (m == 0) ? QF : KF;
            size_t fa = ((((size_t)n * 128 + (p >> 5)) * 6 + c6) * 64
                         + (lg >> 1) * 32 + (p & 31)) * 8 + (lg & 1) * 4;
            *(ushort4*)(dst + fa) = pk4;
        } else {
            const float bias = bv[c6 * 16 + l15];
            ushort4 pk4;
            pk4.x = f2bf(acc[0] + bias); pk4.y = f2bf(acc[1] + bias);
            pk4.z = f2bf(acc[2] + bias); pk4.w = f2bf(acc[3] + bias);
            const int ch = c6 * 16 + l15;
            const int slot = 2 * (w & 3) + (lg >> 1);
            size_t fa = ((((((size_t)n * 64 + bx) * 3 + (ch >> 5)) * 2
                           + (slot >> 2)) * 2 + ((slot >> 1) & 1)) * 64
                         + (slot & 1) * 32 + (ch & 31)) * 8 + (lg & 1) * 4;
            *(ushort4*)(VF + fa) = pk4;
        }
    }
}

// ---------------------------------------------------------------------------
// Kernel 2: attention core — NO LDS, NO barriers (R13 structure) + K-fragment
// register double-buffer: kf for tile t+1 is loaded during tile t's compute,
// so the S-MFMA never waits on a just-issued L2 load.  64 q-rows/wave,
// grid 512 = 8n * 16iblk * 4js, n == XCD.
// ---------------------------------------------------------------------------
__global__ __launch_bounds__(256, 2) void attn_kernel(
    const unsigned short* __restrict__ QF, const unsigned short* __restrict__ KF,
    const unsigned short* __restrict__ VF,
    unsigned short* __restrict__ zp, float* __restrict__ lp)
{
    const int bid = blockIdx.x;           // 512 = 8 n * 16 iblk * 4 js
    const int n    = bid & 7;
    const int iblk = (bid >> 3) & 15;
    const int js   = bid >> 7;            // 0..3

    const int t = threadIdx.x, w = t >> 6, lane = t & 63;
    const int l31 = lane & 31, hi = lane >> 5;
    const int ib = iblk * 256 + w * 64;

    const unsigned short* QFb = QF + (size_t)n * 128 * 3072;
    const unsigned short* KFb = KF + (size_t)n * 128 * 3072;
    const unsigned short* VFb = VF + (size_t)n * 64 * 6144;

    bf16x8 qf[2][6];
    #pragma unroll
    for (int is = 0; is < 2; ++is)
        #pragma unroll
        for (int kc = 0; kc < 6; ++kc)
            qf[is][kc] = *(const bf16x8*)(QFb + ((size_t)((ib >> 5) + is) * 6 + kc) * 512
                                          + lane * 8);

    f32x16 O[2][3];
    #pragma unroll
    for (int is = 0; is < 2; ++is)
        #pragma unroll
        for (int cc = 0; cc < 3; ++cc)
            #pragma unroll
            for (int e = 0; e < 16; ++e) O[is][cc][e] = 0.f;
    float lsum0 = 0.f, lsum1 = 0.f;

    const int jt0 = js * 32;

    // preload K fragments for the first tile
    bf16x8 kfA[6], kfB[6];
    #pragma unroll
    for (int kc = 0; kc < 6; ++kc)
        kfA[kc] = *(const bf16x8*)(KFb + (size_t)jt0 * 3072 + kc * 512 + lane * 8);

#define TILE_BODY(JT, KFCUR, KFNXT, PFJT) do {                                 \
    /* V fragments for this tile (consumed after softmax: ~600cy hide) */      \
    const unsigned short* Vt = VFb + ((size_t)((JT) >> 1) * 12                 \
                                      + ((JT) & 1) * 2) * 512;                 \
    bf16x8 vf[2][3];                                                           \
    _Pragma("unroll") for (int jc = 0; jc < 2; ++jc)                           \
        _Pragma("unroll") for (int cc = 0; cc < 3; ++cc)                       \
            vf[jc][cc] = *(const bf16x8*)(Vt + cc * 2048 + jc * 512            \
                                          + lane * 8);                         \
    /* prefetch next tile's K fragments (consumed next body: full-tile hide)*/ \
    const unsigned short* Kn = KFb + (size_t)(PFJT) * 3072;                    \
    _Pragma("unroll") for (int kc = 0; kc < 6; ++kc)                           \
        KFNXT[kc] = *(const bf16x8*)(Kn + kc * 512 + lane * 8);                \
    /* S^T = mfma(K, Q) */                                                     \
    f32x16 s0, s1;                                                             \
    _Pragma("unroll") for (int e = 0; e < 16; ++e) { s0[e] = 0.f; s1[e] = 0.f; } \
    __builtin_amdgcn_s_setprio(1);                                             \
    _Pragma("unroll") for (int kc = 0; kc < 6; ++kc) {                         \
        s0 = __builtin_amdgcn_mfma_f32_32x32x16_bf16(KFCUR[kc], qf[0][kc], s0, 0, 0, 0); \
        s1 = __builtin_amdgcn_mfma_f32_32x32x16_bf16(KFCUR[kc], qf[1][kc], s1, 0, 0, 0); \
    }                                                                          \
    __builtin_amdgcn_s_setprio(0);                                             \
    /* P = exp2(S); in-lane row sums; pack to bf16 */                          \
    unsigned pkk[2][4][2];                                                     \
    _Pragma("unroll") for (int q = 0; q < 4; ++q)                              \
        _Pragma("unroll") for (int rp = 0; rp < 2; ++rp) {                     \
            float lo0 = __builtin_exp2f(s0[q * 4 + 2 * rp]);                   \
            float hh0 = __builtin_exp2f(s0[q * 4 + 2 * rp + 1]);               \
            float lo1 = __builtin_exp2f(s1[q * 4 + 2 * rp]);                   \
            float hh1 = __builtin_exp2f(s1[q * 4 + 2 * rp + 1]);               \
            lsum0 += lo0 + hh0;                                                \
            lsum1 += lo1 + hh1;                                                \
            asm("v_cvt_pk_bf16_f32 %0, %1, %2"                                 \
                : "=v"(pkk[0][q][rp]) : "v"(lo0), "v"(hh0));                   \
            asm("v_cvt_pk_bf16_f32 %0, %1, %2"                                 \
                : "=v"(pkk[1][q][rp]) : "v"(lo1), "v"(hh1));                   \
        }                                                                      \
    /* redistribute to PV A-frags (lane<32 <-> lane>=32 halves) */             \
    u32x4 pfu[2][2];                                                           \
    _Pragma("unroll") for (int is = 0; is < 2; ++is)                           \
        _Pragma("unroll") for (int jc = 0; jc < 2; ++jc) {                     \
            unsigned x0 = pkk[is][2 * jc][0], y0 = pkk[is][2 * jc + 1][0];     \
            unsigned x1 = pkk[is][2 * jc][1], y1 = pkk[is][2 * jc + 1][1];     \
            asm("v_permlane32_swap_b32 %0, %1" : "+v"(y0), "+v"(x0));          \
            asm("v_permlane32_swap_b32 %0, %1" : "+v"(y1), "+v"(x1));          \
            pfu[is][jc][0] = x0; pfu[is][jc][1] = x1;                          \
            pfu[is][jc][2] = y0; pfu[is][jc][3] = y1;                          \
        }                                                                      \
    /* O += P V */                                                             \
    __builtin_amdgcn_s_setprio(1);                                             \
    _Pragma("unroll") for (int jc = 0; jc < 2; ++jc) {                         \
        bf16x8 pa0 = __builtin_bit_cast(bf16x8, pfu[0][jc]);                   \
        bf16x8 pa1 = __builtin_bit_cast(bf16x8, pfu[1][jc]);                   \
        _Pragma("unroll") for (int cc = 0; cc < 3; ++cc) {                     \
            O[0][cc] = __builtin_amdgcn_mfma_f32_32x32x16_bf16(pa0, vf[jc][cc], O[0][cc], 0, 0, 0); \
            O[1][cc] = __builtin_amdgcn_mfma_f32_32x32x16_bf16(pa1, vf[jc][cc], O[1][cc], 0, 0, 0); \
        }                                                                      \
    }                                                                          \
    __builtin_amdgcn_s_setprio(0);                                             \
} while (0)

    for (int tt = 0; tt < 32; tt += 2) {
        const int jt = jt0 + tt;
        TILE_BODY(jt, kfA, kfB, jt + 1);
        const int pf2 = (tt + 2 < 32) ? jt + 2 : jt + 1;  // clamp at slice end
        TILE_BODY(jt + 1, kfB, kfA, pf2);
    }
#undef TILE_BODY

    // ---- epilogue: unnormalized O (bf16) + row sums
    unsigned short* zb = zp + ((size_t)js * 8 + n) * HW * CMID;
    #pragma unroll
    for (int is = 0; is < 2; ++is)
        #pragma unroll
        for (int cc = 0; cc < 3; ++cc)
            #pragma unroll
            for (int r = 0; r < 16; ++r) {
                int i = ib + is * 32 + (r & 3) + 8 * (r >> 2) + 4 * hi;
                zb[(size_t)i * CMID + cc * 32 + l31] = f2bf(O[is][cc][r]);
            }

    lsum0 += __shfl_xor(lsum0, 32, 64);
    lsum1 += __shfl_xor(lsum1, 32, 64);
    if (hi == 0) {
        float* lb = lp + ((size_t)js * 8 + n) * HW;
        lb[ib + l31]      = lsum0;
        lb[ib + 32 + l31] = lsum1;
    }
}

// ---------------------------------------------------------------------------
// Kernel 3: combine 4 j-slices, normalize, project back (MFMA), residual.
// (R13 JS=4 version, unchanged.)
// ---------------------------------------------------------------------------
__global__ __launch_bounds__(256) void zproj_kernel(
    const unsigned short* __restrict__ zp, const float* __restrict__ lp,
    const unsigned short* __restrict__ wzb, const float* __restrict__ bz,
    const float* __restrict__ x, const float* __restrict__ pe,
    float* __restrict__ out)
{
    const int n = blockIdx.y, i0 = blockIdx.x * 64, t = threadIdx.x;
    __shared__ unsigned short zt[64 * 104];
    __shared__ float ll[64];

    if (t < 64) {
        float s = 0.f;
        #pragma unroll
        for (int sl = 0; sl < 4; ++sl)
            s += lp[(size_t)sl * 8 * HW + (size_t)n * HW + i0 + t];
        ll[t] = 1.f / s;
    }
    __syncthreads();

    #pragma unroll
    for (int u = 0; u < 3; ++u) {
        int unit = t + u * 256;
        int i = unit / 12, g = unit % 12;
        size_t gidx = ((size_t)n * HW + i0 + i) * CMID + g * 8;
        float a[8];
        #pragma unroll
        for (int e = 0; e < 8; ++e) a[e] = 0.f;
        #pragma unroll
        for (int sl = 0; sl < 4; ++sl) {
            u32x4 wv = *(const u32x4*)(zp + (size_t)sl * 8 * HW * CMID + gidx);
            #pragma unroll
            for (int k = 0; k < 4; ++k) {
                union { unsigned u; float f; } lo, hi2;
                lo.u = wv[k] << 16;
                hi2.u = wv[k] & 0xffff0000u;
                a[2 * k]     += lo.f;
                a[2 * k + 1] += hi2.f;
            }
        }
        float li = ll[i];
        unsigned ww[4];
        #pragma unroll
        for (int k = 0; k < 4; ++k) {
            float p0 = a[2 * k] * li, p1 = a[2 * k + 1] * li;
            asm("v_cvt_pk_bf16_f32 %0, %1, %2" : "=v"(ww[k]) : "v"(p0), "v"(p1));
        }
        u32x4 wv4 = {ww[0], ww[1], ww[2], ww[3]};
        *(u32x4*)(zt + i * 104 + g * 8) = wv4;
    }
    __syncthreads();

    const int w = t >> 6, lane = t & 63, l15 = lane & 15, lg = lane >> 4;
    const int p0 = w * 16;

    bf16x8 af[3];
    #pragma unroll
    for (int f = 0; f < 3; ++f)
        af[f] = *(const bf16x8*)(zt + (p0 + l15) * 104 + f * 32 + lg * 8);

    #pragma unroll
    for (int ct = 0; ct < 12; ++ct) {
        f32x4 acc = (f32x4){0.f, 0.f, 0.f, 0.f};
        const unsigned short* wrow = wzb + (ct * 16 + l15) * CMID + lg * 8;
        #pragma unroll
        for (int f = 0; f < 3; ++f) {
            bf16x8 wf = *(const bf16x8*)(wrow + f * 32);
            acc = __builtin_amdgcn_mfma_f32_16x16x32_bf16(af[f], wf, acc, 0, 0, 0);
        }
        const int co = ct * 16 + l15;
        const int ibase = i0 + p0 + lg * 4;
        size_t xa = ((size_t)n * CIN + co) * HW + ibase;
        f32x4 xv = *(const f32x4*)(x + xa);
        f32x4 pv = *(const f32x4*)(pe + co * 14400 + blockIdx.x * 120 + p0 + lg * 4);
        const float bias = bz[co];
        f32x4 o;
        #pragma unroll
        for (int r = 0; r < 4; ++r) o[r] = xv[r] + pv[r] + acc[r] + bias;
        *(f32x4*)(out + xa) = o;
    }
}

// ---------------------------------------------------------------------------
extern "C" void kernel_launch(void* const* d_in, const int* in_sizes, int n_in,
                              void* d_out, int out_size, void* d_ws, size_t ws_size,
                              hipStream_t stream) {
    const float* x  = (const float*)d_in[0];
    const float* pe = (const float*)d_in[1];
    const float* wq = (const float*)d_in[2];
    const float* bq = (const float*)d_in[3];
    const float* wk = (const float*)d_in[4];
    const float* bk = (const float*)d_in[5];
    const float* wv = (const float*)d_in[6];
    const float* bv = (const float*)d_in[7];
    const float* wz = (const float*)d_in[8];
    const float* bz = (const float*)d_in[9];
    float* out = (float*)d_out;

    char* ws = (char*)d_ws;
    // ws layout (bytes) — JS=4 (R13-proven):
    //        0: wqkvb bf16 [288][192]          110,592 (pad 131072)
    //   131072: wzb   bf16 [192][96]            36,864 (pad 65536)
    //   196608: QF bf16 [8][128][6][64][8]    6,291,456
    //  6488064: KF bf16 (same shape)          6,291,456
    // 12779520: VF bf16 [8][64][3][2][2][64][8] 6,291,456
    // 19070976: zp bf16 [4][8][4096][96]     25,165,824
    // 44236800: lp f32 [4][8][4096]             524,288   (end 44,761,088)
    unsigned short* wqkvb = (unsigned short*)(ws);
    unsigned short* wzb   = (unsigned short*)(ws + 131072);
    unsigned short* QFb   = (unsigned short*)(ws + 196608);
    unsigned short* KFb   = (unsigned short*)(ws + 6488064);
    unsigned short* VFb   = (unsigned short*)(ws + 12779520);
    unsigned short* zpb   = (unsigned short*)(ws + 19070976);
    float*          lpb   = (float*)(ws + 44236800);

    convw_kernel<<<288, 256, 0, stream>>>(wq, wk, wv, wz, wqkvb, wzb);
    qkv_kernel<<<dim3(64, 8), 512, 0, stream>>>(x, pe, wqkvb, bq, bk, bv,
                                                QFb, KFb, VFb);
    attn_kernel<<<512, 256, 0, stream>>>(QFb, KFb, VFb, zpb, lpb);
    zproj_kernel<<<dim3(64, 8), 256, 0, stream>>>(zpb, lpb, wzb, bz, x, pe, out);
}

// Round 17
// 118.149 us; speedup vs baseline: 1.1831x; 1.1831x over previous
//
#include <hip/hip_runtime.h>
#include <hip/hip_bf16.h>

#define HW 4096
#define CIN 192
#define CMID 96

typedef __attribute__((ext_vector_type(8))) short bf16x8;
typedef __attribute__((ext_vector_type(4))) float f32x4;
typedef __attribute__((ext_vector_type(16))) float f32x16;
typedef __attribute__((ext_vector_type(4))) unsigned int u32x4;

static __device__ __forceinline__ unsigned short f2bf(float f) {
    union { float f; unsigned int u; } v;
    v.f = f;
    unsigned int r = v.u + 0x7fffu + ((v.u >> 16) & 1u);
    return (unsigned short)(r >> 16);
}

// (1/64) * log2(e), folded into Q at projection time
#define SCQ (0.015625f * 1.44269504089f)

// ---------------------------------------------------------------------------
// Kernel 0: convert weights to bf16.
// ---------------------------------------------------------------------------
__global__ __launch_bounds__(256) void convw_kernel(
    const float* __restrict__ wq, const float* __restrict__ wk,
    const float* __restrict__ wv, const float* __restrict__ wz,
    unsigned short* __restrict__ wqkvb, unsigned short* __restrict__ wzb)
{
    int idx = blockIdx.x * 256 + threadIdx.x;
    if (idx < 3 * CMID * CIN) {
        int m = idx / (CMID * CIN), r = idx % (CMID * CIN);
        const float* w = (m == 0) ? wq : ((m == 1) ? wk : wv);
        wqkvb[idx] = f2bf(w[r]);
    } else if (idx < 3 * CMID * CIN + CIN * CMID) {
        int r = idx - 3 * CMID * CIN;
        wzb[r] = f2bf(wz[r]);
    }
}

// ---------------------------------------------------------------------------
// Kernel 1: Q/K/V projections (bf16 MFMA), fragment-major outputs.
// (R13 verbatim.)
// ---------------------------------------------------------------------------
__global__ __launch_bounds__(512) void qkv_kernel(
    const float* __restrict__ x, const float* __restrict__ pe,
    const unsigned short* __restrict__ wqkvb,
    const float* __restrict__ bq, const float* __restrict__ bk,
    const float* __restrict__ bv,
    unsigned short* __restrict__ QF, unsigned short* __restrict__ KF,
    unsigned short* __restrict__ VF)
{
    const int n = blockIdx.y, bx = blockIdx.x, i0 = bx * 64, t = threadIdx.x;
    __shared__ unsigned short xt[64 * 200];

    #pragma unroll
    for (int it = 0; it < 6; ++it) {
        int q = t + it * 512;
        int c = q >> 4, il4 = (q & 15) << 2;
        f32x4 xv = *(const f32x4*)(x + ((size_t)n * CIN + c) * HW + i0 + il4);
        f32x4 pv = *(const f32x4*)(pe + c * 14400 + bx * 120 + il4);
        float a0 = xv[0] + pv[0], a1 = xv[1] + pv[1];
        float a2 = xv[2] + pv[2], a3 = xv[3] + pv[3];
        unsigned w01, w23;
        asm("v_cvt_pk_bf16_f32 %0, %1, %2" : "=v"(w01) : "v"(a0), "v"(a1));
        asm("v_cvt_pk_bf16_f32 %0, %1, %2" : "=v"(w23) : "v"(a2), "v"(a3));
        xt[(il4 + 0) * 200 + c] = (unsigned short)w01;
        xt[(il4 + 1) * 200 + c] = (unsigned short)(w01 >> 16);
        xt[(il4 + 2) * 200 + c] = (unsigned short)w23;
        xt[(il4 + 3) * 200 + c] = (unsigned short)(w23 >> 16);
    }
    __syncthreads();

    const int w = t >> 6, lane = t & 63, l15 = lane & 15, lg = lane >> 4;
    const int wg = w >> 2;
    const int p0 = (w & 3) * 16;

    bf16x8 af[6];
    #pragma unroll
    for (int f = 0; f < 6; ++f)
        af[f] = *(const bf16x8*)(xt + (p0 + l15) * 200 + f * 32 + lg * 8);

    #pragma unroll
    for (int cc = 0; cc < 9; ++cc) {
        const int ct = wg * 9 + cc;
        const int m = ct / 6, c6 = ct % 6;
        f32x4 acc = (f32x4){0.f, 0.f, 0.f, 0.f};
        const unsigned short* wrow = wqkvb + (ct * 16 + l15) * CIN + lg * 8;
        #pragma unroll
        for (int f = 0; f < 6; ++f) {
            bf16x8 wf = *(const bf16x8*)(wrow + f * 32);
            if (m < 2)
                acc = __builtin_amdgcn_mfma_f32_16x16x32_bf16(wf, af[f], acc, 0, 0, 0);
            else
                acc = __builtin_amdgcn_mfma_f32_16x16x32_bf16(af[f], wf, acc, 0, 0, 0);
        }
        if (m < 2) {
            f32x4 bv4 = *(const f32x4*)(((m == 0) ? bq : bk) + c6 * 16 + lg * 4);
            ushort4 pk4;
            if (m == 0) {
                pk4.x = f2bf((acc[0] + bv4[0]) * SCQ);
                pk4.y = f2bf((acc[1] + bv4[1]) * SCQ);
                pk4.z = f2bf((acc[2] + bv4[2]) * SCQ);
                pk4.w = f2bf((acc[3] + bv4[3]) * SCQ);
            } else {
                pk4.x = f2bf(acc[0] + bv4[0]);
                pk4.y = f2bf(acc[1] + bv4[1]);
                pk4.z = f2bf(acc[2] + bv4[2]);
                pk4.w = f2bf(acc[3] + bv4[3]);
            }
            const int p = i0 + p0 + l15;
            unsigned short* dst = (m == 0) ? QF : KF;
            size_t fa = ((((size_t)n * 128 + (p >> 5)) * 6 + c6) * 64
                         + (lg >> 1) * 32 + (p & 31)) * 8 + (lg & 1) * 4;
            *(ushort4*)(dst + fa) = pk4;
        } else {
            const float bias = bv[c6 * 16 + l15];
            ushort4 pk4;
            pk4.x = f2bf(acc[0] + bias); pk4.y = f2bf(acc[1] + bias);
            pk4.z = f2bf(acc[2] + bias); pk4.w = f2bf(acc[3] + bias);
            const int ch = c6 * 16 + l15;
            const int slot = 2 * (w & 3) + (lg >> 1);
            size_t fa = ((((((size_t)n * 64 + bx) * 3 + (ch >> 5)) * 2
                           + (slot >> 2)) * 2 + ((slot >> 1) & 1)) * 64
                         + (slot & 1) * 32 + (ch & 31)) * 8 + (lg & 1) * 4;
            *(ushort4*)(VF + fa) = pk4;
        }
    }
}

// ---------------------------------------------------------------------------
// Kernel 2: attention core — NO LDS, NO barriers.  Fragments read directly
// from L2 in fragment-major layout (coalesced 1KB wave bursts).  64 q-rows
// per wave, 4 waves/block (independent), grid 512 = 8n * 16iblk * 4js,
// n == XCD so each XCD's K/V slice stays L2-resident.  (R13 verbatim.)
// ---------------------------------------------------------------------------
__global__ __launch_bounds__(256, 2) void attn_kernel(
    const unsigned short* __restrict__ QF, const unsigned short* __restrict__ KF,
    const unsigned short* __restrict__ VF,
    unsigned short* __restrict__ zp, float* __restrict__ lp)
{
    const int bid = blockIdx.x;           // 512 = 8 n * 16 iblk * 4 js
    const int n    = bid & 7;
    const int iblk = (bid >> 3) & 15;
    const int js   = bid >> 7;            // 0..3

    const int t = threadIdx.x, w = t >> 6, lane = t & 63;
    const int l31 = lane & 31, hi = lane >> 5;
    const int ib = iblk * 256 + w * 64;

    const unsigned short* QFb = QF + (size_t)n * 128 * 3072;
    const unsigned short* KFb = KF + (size_t)n * 128 * 3072;
    const unsigned short* VFb = VF + (size_t)n * 64 * 6144;

    bf16x8 qf[2][6];
    #pragma unroll
    for (int is = 0; is < 2; ++is)
        #pragma unroll
        for (int kc = 0; kc < 6; ++kc)
            qf[is][kc] = *(const bf16x8*)(QFb + ((size_t)((ib >> 5) + is) * 6 + kc) * 512
                                          + lane * 8);

    f32x16 O[2][3];
    #pragma unroll
    for (int is = 0; is < 2; ++is)
        #pragma unroll
        for (int cc = 0; cc < 3; ++cc)
            #pragma unroll
            for (int e = 0; e < 16; ++e) O[is][cc][e] = 0.f;
    float lsum0 = 0.f, lsum1 = 0.f;

    for (int tt = 0; tt < 32; ++tt) {
        const int jt = js * 32 + tt;
        const unsigned short* Kt = KFb + (size_t)jt * 3072;

        // all 12 fragment loads issued up front (independent, coalesced)
        bf16x8 kf[6];
        #pragma unroll
        for (int kc = 0; kc < 6; ++kc)
            kf[kc] = *(const bf16x8*)(Kt + kc * 512 + lane * 8);
        bf16x8 vf[2][3];
        #pragma unroll
        for (int jc = 0; jc < 2; ++jc)
            #pragma unroll
            for (int cc = 0; cc < 3; ++cc)
                vf[jc][cc] = *(const bf16x8*)(VFb
                    + ((size_t)((jt >> 1) * 3 + cc) * 4 + (jt & 1) * 2 + jc) * 512
                    + lane * 8);

        // S^T = mfma(K, Q): D[j][i]
        f32x16 s0, s1;
        #pragma unroll
        for (int e = 0; e < 16; ++e) { s0[e] = 0.f; s1[e] = 0.f; }
        __builtin_amdgcn_s_setprio(1);
        #pragma unroll
        for (int kc = 0; kc < 6; ++kc) {
            s0 = __builtin_amdgcn_mfma_f32_32x32x16_bf16(kf[kc], qf[0][kc], s0, 0, 0, 0);
            s1 = __builtin_amdgcn_mfma_f32_32x32x16_bf16(kf[kc], qf[1][kc], s1, 0, 0, 0);
        }
        __builtin_amdgcn_s_setprio(0);

        // P = exp2(S); in-lane row sums; pack to bf16
        unsigned pkk[2][4][2];
        #pragma unroll
        for (int q = 0; q < 4; ++q)
            #pragma unroll
            for (int rp = 0; rp < 2; ++rp) {
                float lo0 = __builtin_exp2f(s0[q * 4 + 2 * rp]);
                float hh0 = __builtin_exp2f(s0[q * 4 + 2 * rp + 1]);
                float lo1 = __builtin_exp2f(s1[q * 4 + 2 * rp]);
                float hh1 = __builtin_exp2f(s1[q * 4 + 2 * rp + 1]);
                lsum0 += lo0 + hh0;
                lsum1 += lo1 + hh1;
                asm("v_cvt_pk_bf16_f32 %0, %1, %2"
                    : "=v"(pkk[0][q][rp]) : "v"(lo0), "v"(hh0));
                asm("v_cvt_pk_bf16_f32 %0, %1, %2"
                    : "=v"(pkk[1][q][rp]) : "v"(lo1), "v"(hh1));
            }

        // redistribute to PV A-frags (lane<32 <-> lane>=32 halves)
        u32x4 pfu[2][2];
        #pragma unroll
        for (int is = 0; is < 2; ++is)
            #pragma unroll
            for (int jc = 0; jc < 2; ++jc) {
                unsigned x0 = pkk[is][2 * jc][0], y0 = pkk[is][2 * jc + 1][0];
                unsigned x1 = pkk[is][2 * jc][1], y1 = pkk[is][2 * jc + 1][1];
                asm("v_permlane32_swap_b32 %0, %1" : "+v"(y0), "+v"(x0));
                asm("v_permlane32_swap_b32 %0, %1" : "+v"(y1), "+v"(x1));
                pfu[is][jc][0] = x0; pfu[is][jc][1] = x1;
                pfu[is][jc][2] = y0; pfu[is][jc][3] = y1;
            }

        // O += P V
        __builtin_amdgcn_s_setprio(1);
        #pragma unroll
        for (int jc = 0; jc < 2; ++jc) {
            bf16x8 pa0 = __builtin_bit_cast(bf16x8, pfu[0][jc]);
            bf16x8 pa1 = __builtin_bit_cast(bf16x8, pfu[1][jc]);
            #pragma unroll
            for (int cc = 0; cc < 3; ++cc) {
                O[0][cc] = __builtin_amdgcn_mfma_f32_32x32x16_bf16(pa0, vf[jc][cc], O[0][cc], 0, 0, 0);
                O[1][cc] = __builtin_amdgcn_mfma_f32_32x32x16_bf16(pa1, vf[jc][cc], O[1][cc], 0, 0, 0);
            }
        }
        __builtin_amdgcn_s_setprio(0);
    }

    // ---- epilogue: unnormalized O (bf16) + row sums
    unsigned short* zb = zp + ((size_t)js * 8 + n) * HW * CMID;
    #pragma unroll
    for (int is = 0; is < 2; ++is)
        #pragma unroll
        for (int cc = 0; cc < 3; ++cc)
            #pragma unroll
            for (int r = 0; r < 16; ++r) {
                int i = ib + is * 32 + (r & 3) + 8 * (r >> 2) + 4 * hi;
                zb[(size_t)i * CMID + cc * 32 + l31] = f2bf(O[is][cc][r]);
            }

    lsum0 += __shfl_xor(lsum0, 32, 64);
    lsum1 += __shfl_xor(lsum1, 32, 64);
    if (hi == 0) {
        float* lb = lp + ((size_t)js * 8 + n) * HW;
        lb[ib + l31]      = lsum0;
        lb[ib + 32 + l31] = lsum1;
    }
}

// ---------------------------------------------------------------------------
// Kernel 3: combine 4 j-slices, normalize, project back (MFMA), residual.
// (R13 verbatim.)
// ---------------------------------------------------------------------------
__global__ __launch_bounds__(256) void zproj_kernel(
    const unsigned short* __restrict__ zp, const float* __restrict__ lp,
    const unsigned short* __restrict__ wzb, const float* __restrict__ bz,
    const float* __restrict__ x, const float* __restrict__ pe,
    float* __restrict__ out)
{
    const int n = blockIdx.y, i0 = blockIdx.x * 64, t = threadIdx.x;
    __shared__ unsigned short zt[64 * 104];
    __shared__ float ll[64];

    if (t < 64) {
        float s = 0.f;
        #pragma unroll
        for (int sl = 0; sl < 4; ++sl)
            s += lp[(size_t)sl * 8 * HW + (size_t)n * HW + i0 + t];
        ll[t] = 1.f / s;
    }
    __syncthreads();

    #pragma unroll
    for (int u = 0; u < 3; ++u) {
        int unit = t + u * 256;
        int i = unit / 12, g = unit % 12;
        size_t gidx = ((size_t)n * HW + i0 + i) * CMID + g * 8;
        float a[8];
        #pragma unroll
        for (int e = 0; e < 8; ++e) a[e] = 0.f;
        #pragma unroll
        for (int sl = 0; sl < 4; ++sl) {
            u32x4 wv = *(const u32x4*)(zp + (size_t)sl * 8 * HW * CMID + gidx);
            #pragma unroll
            for (int k = 0; k < 4; ++k) {
                union { unsigned u; float f; } lo, hi2;
                lo.u = wv[k] << 16;
                hi2.u = wv[k] & 0xffff0000u;
                a[2 * k]     += lo.f;
                a[2 * k + 1] += hi2.f;
            }
        }
        float li = ll[i];
        unsigned ww[4];
        #pragma unroll
        for (int k = 0; k < 4; ++k) {
            float p0 = a[2 * k] * li, p1 = a[2 * k + 1] * li;
            asm("v_cvt_pk_bf16_f32 %0, %1, %2" : "=v"(ww[k]) : "v"(p0), "v"(p1));
        }
        u32x4 wv4 = {ww[0], ww[1], ww[2], ww[3]};
        *(u32x4*)(zt + i * 104 + g * 8) = wv4;
    }
    __syncthreads();

    const int w = t >> 6, lane = t & 63, l15 = lane & 15, lg = lane >> 4;
    const int p0 = w * 16;

    bf16x8 af[3];
    #pragma unroll
    for (int f = 0; f < 3; ++f)
        af[f] = *(const bf16x8*)(zt + (p0 + l15) * 104 + f * 32 + lg * 8);

    #pragma unroll
    for (int ct = 0; ct < 12; ++ct) {
        f32x4 acc = (f32x4){0.f, 0.f, 0.f, 0.f};
        const unsigned short* wrow = wzb + (ct * 16 + l15) * CMID + lg * 8;
        #pragma unroll
        for (int f = 0; f < 3; ++f) {
            bf16x8 wf = *(const bf16x8*)(wrow + f * 32);
            acc = __builtin_amdgcn_mfma_f32_16x16x32_bf16(af[f], wf, acc, 0, 0, 0);
        }
        const int co = ct * 16 + l15;
        const int ibase = i0 + p0 + lg * 4;
        size_t xa = ((size_t)n * CIN + co) * HW + ibase;
        f32x4 xv = *(const f32x4*)(x + xa);
        f32x4 pv = *(const f32x4*)(pe + co * 14400 + blockIdx.x * 120 + p0 + lg * 4);
        const float bias = bz[co];
        f32x4 o;
        #pragma unroll
        for (int r = 0; r < 4; ++r) o[r] = xv[r] + pv[r] + acc[r] + bias;
        *(f32x4*)(out + xa) = o;
    }
}

// ---------------------------------------------------------------------------
extern "C" void kernel_launch(void* const* d_in, const int* in_sizes, int n_in,
                              void* d_out, int out_size, void* d_ws, size_t ws_size,
                              hipStream_t stream) {
    const float* x  = (const float*)d_in[0];
    const float* pe = (const float*)d_in[1];
    const float* wq = (const float*)d_in[2];
    const float* bq = (const float*)d_in[3];
    const float* wk = (const float*)d_in[4];
    const float* bk = (const float*)d_in[5];
    const float* wv = (const float*)d_in[6];
    const float* bv = (const float*)d_in[7];
    const float* wz = (const float*)d_in[8];
    const float* bz = (const float*)d_in[9];
    float* out = (float*)d_out;

    char* ws = (char*)d_ws;
    // ws layout (bytes) — JS=4 (R13-proven):
    //        0: wqkvb bf16 [288][192]          110,592 (pad 131072)
    //   131072: wzb   bf16 [192][96]            36,864 (pad 65536)
    //   196608: QF bf16 [8][128][6][64][8]    6,291,456
    //  6488064: KF bf16 (same shape)          6,291,456
    // 12779520: VF bf16 [8][64][3][2][2][64][8] 6,291,456
    // 19070976: zp bf16 [4][8][4096][96]     25,165,824
    // 44236800: lp f32 [4][8][4096]             524,288   (end 44,761,088)
    unsigned short* wqkvb = (unsigned short*)(ws);
    unsigned short* wzb   = (unsigned short*)(ws + 131072);
    unsigned short* QFb   = (unsigned short*)(ws + 196608);
    unsigned short* KFb   = (unsigned short*)(ws + 6488064);
    unsigned short* VFb   = (unsigned short*)(ws + 12779520);
    unsigned short* zpb   = (unsigned short*)(ws + 19070976);
    float*          lpb   = (float*)(ws + 44236800);

    convw_kernel<<<288, 256, 0, stream>>>(wq, wk, wv, wz, wqkvb, wzb);
    qkv_kernel<<<dim3(64, 8), 512, 0, stream>>>(x, pe, wqkvb, bq, bk, bv,
                                                QFb, KFb, VFb);
    attn_kernel<<<512, 256, 0, stream>>>(QFb, KFb, VFb, zpb, lpb);
    zproj_kernel<<<dim3(64, 8), 256, 0, stream>>>(zpb, lpb, wzb, bz, x, pe, out);
}